// Round 10
// baseline (152.801 us; speedup 1.0000x reference)
//
#include <hip/hip_runtime.h>
#include <hip/hip_bf16.h>
#include <cfloat>
#include <climits>
#include <cstdint>

#define ALPHA 30.0f
#define KSEL 16          // threshold = sorted[:,16] (17th smallest off-diag)
#define P0 1.368f        // candidate cutoff: E[cnt/row]≈82, P(cnt<17)~1e-13
#define P0SQ (P0 * P0)
#define CAP 224          // per-row candidate capacity (mean 82, +15 sigma)
#define TCAP 896         // per-tile candidate capacity (mean 330, +31 sigma)
#define BIGV 1e30f
#define NMAX 4096

typedef __attribute__((ext_vector_type(8))) short bf16x8;
typedef __attribute__((ext_vector_type(4))) float f32x4;

#define LDS_PTR(p) ((__attribute__((address_space(3))) uint32_t*)(p))
#define GLB_PTR(p) ((const __attribute__((address_space(1))) uint32_t*)(p))

__device__ inline float bfval(ushort u) {
    return __builtin_bit_cast(float, (uint32_t)u << 16);
}

// ---------------------------------------------------------------------------
// block reduce helpers (256 threads, 4 waves)
// ---------------------------------------------------------------------------
__device__ inline float blockReduceSumF(float v, float* s) {
    for (int off = 32; off; off >>= 1) v += __shfl_down(v, off);
    int tid = threadIdx.x, wid = tid >> 6;
    if ((tid & 63) == 0) s[wid] = v;
    __syncthreads();
    float r;
    if (tid == 0) { r = s[0] + s[1] + s[2] + s[3]; s[0] = r; }
    __syncthreads();
    r = s[0];
    __syncthreads();
    return r;
}

__device__ inline int blockReduceSumI(int v, int* s) {
    for (int off = 32; off; off >>= 1) v += __shfl_down(v, off);
    int tid = threadIdx.x, wid = tid >> 6;
    if ((tid & 63) == 0) s[wid] = v;
    __syncthreads();
    int r;
    if (tid == 0) { r = s[0] + s[1] + s[2] + s[3]; s[0] = r; }
    __syncthreads();
    r = s[0];
    __syncthreads();
    return r;
}

__device__ inline int blockReduceMaxI(int v, int* s) {
    for (int off = 32; off; off >>= 1) v = max(v, __shfl_down(v, off));
    int tid = threadIdx.x, wid = tid >> 6;
    if ((tid & 63) == 0) s[wid] = v;
    __syncthreads();
    int r;
    if (tid == 0) { r = max(max(s[0], s[1]), max(s[2], s[3])); s[0] = r; }
    __syncthreads();
    r = s[0];
    __syncthreads();
    return r;
}

// ---------------------------------------------------------------------------
// Kernel 1: fused fp32->bf16 (RNE) + row sq-norm; blocks >= N do labelinfo.
// ---------------------------------------------------------------------------
__global__ __launch_bounds__(256) void prep_kernel(const float* __restrict__ X,
                                                   ushort* __restrict__ Xb,
                                                   float* __restrict__ sq,
                                                   const int* __restrict__ targets,
                                                   int* __restrict__ f1,
                                                   int* __restrict__ f2,
                                                   int* __restrict__ lcnt,
                                                   int D, int N) {
    __shared__ float sw[4];
    __shared__ int s1[4], s2[4], sc[4];
    int tid = threadIdx.x;
    int wid = tid >> 6;

    if (blockIdx.x >= (unsigned)N) {
        // ---- labelinfo: per-label two smallest indices + count ----
        int lbl = blockIdx.x - N;
        int a1 = INT_MAX, a2 = INT_MAX, c = 0;
        for (int j = tid; j < N; j += 256) {
            if (targets[j] == lbl) {
                ++c;
                if (j < a1) { a2 = a1; a1 = j; }
                else if (j < a2) a2 = j;
            }
        }
        for (int off = 32; off; off >>= 1) {
            int b1 = __shfl_down(a1, off), b2 = __shfl_down(a2, off), bc = __shfl_down(c, off);
            int m1 = min(a1, b1);
            int m2 = min(max(a1, b1), min(a2, b2));
            a1 = m1; a2 = m2; c += bc;
        }
        if ((tid & 63) == 0) { s1[wid] = a1; s2[wid] = a2; sc[wid] = c; }
        __syncthreads();
        if (tid == 0) {
            int r1 = s1[0], r2 = s2[0], rc = sc[0];
            for (int w = 1; w < 4; ++w) {
                int m1 = min(r1, s1[w]);
                int m2 = min(max(r1, s1[w]), min(r2, s2[w]));
                r1 = m1; r2 = m2; rc += sc[w];
            }
            f1[lbl] = r1; f2[lbl] = r2; lcnt[lbl] = rc;
        }
        return;
    }

    int row = blockIdx.x;
    const float4* xr = reinterpret_cast<const float4*>(X + (size_t)row * D);
    ushort4* xo = reinterpret_cast<ushort4*>(Xb + (size_t)row * D);
    float s = 0.f;
    for (int c = tid; c < D / 4; c += 256) {
        float4 v = xr[c];
        s += v.x * v.x + v.y * v.y + v.z * v.z + v.w * v.w;
        ushort4 o;
        uint32_t b;
        b = __builtin_bit_cast(uint32_t, v.x); o.x = (ushort)((b + 0x7FFF + ((b >> 16) & 1)) >> 16);
        b = __builtin_bit_cast(uint32_t, v.y); o.y = (ushort)((b + 0x7FFF + ((b >> 16) & 1)) >> 16);
        b = __builtin_bit_cast(uint32_t, v.z); o.z = (ushort)((b + 0x7FFF + ((b >> 16) & 1)) >> 16);
        b = __builtin_bit_cast(uint32_t, v.w); o.w = (ushort)((b + 0x7FFF + ((b >> 16) & 1)) >> 16);
        xo[c] = o;
    }
    for (int off = 32; off; off >>= 1) s += __shfl_down(s, off);
    if ((tid & 63) == 0) sw[wid] = s;
    __syncthreads();
    if (tid == 0) sq[row] = sw[0] + sw[1] + sw[2] + sw[3];
}

// ---------------------------------------------------------------------------
// Kernel 2: bf16 MFMA GEMM with BARRIER-FREE K-loop.
// Each wave stages its own A-half/B-half into PRIVATE LDS (2x L2 traffic,
// no cross-wave dependency) and syncs only via counted s_waitcnt vmcnt(8)
// (AITER pattern: never drain to 0 in the loop, no s_barrier).
// Candidates (v < P0^2, off-diag) ballot-compacted to LDS, bulk-written.
// ---------------------------------------------------------------------------
#define GBM 128
#define GBK 32
__global__ __launch_bounds__(256) void distgemm_mfma(const ushort* __restrict__ Xb,
                                                     const float* __restrict__ sq,
                                                     float2* __restrict__ tileList,
                                                     int* __restrict__ tileCnt,
                                                     int* __restrict__ needFB,
                                                     int N, int D) {
    // per-wave private double-buffered halves: 4 waves x 2 bufs x 64x32 bf16
    __shared__ ushort As[4][2][64 * GBK];   // 32 KB
    __shared__ ushort Bs[4][2][64 * GBK];   // 32 KB
    __shared__ float2 tlist[TCAP];          // 7 KB
    __shared__ int s_cnt;

    // XCD-aware swizzle: 1024 blocks, 8 XCDs -> contiguous row-panels per XCD.
    int wg = blockIdx.x;
    int wgid = (wg & 7) * 128 + (wg >> 3);
    int by = wgid >> 5, bx = wgid & 31;

    int tid = threadIdx.x;
    int lane = tid & 63;
    int wave = tid >> 6;
    int waveR = wave >> 1;
    int waveC = wave & 1;

    int rowBase = by * GBM;
    int colBase = bx * GBM;

    if (tid == 0) s_cnt = 0;
    __syncthreads();   // publish s_cnt=0 (only barrier before epilogue)

    f32x4 acc[4][4];
#pragma unroll
    for (int m = 0; m < 4; ++m)
#pragma unroll
        for (int n2 = 0; n2 < 4; ++n2) {
            f32x4 z = {0.f, 0.f, 0.f, 0.f};
            acc[m][n2] = z;
        }

    // wave stages ONLY its own rows: A rows [waveR*64,+64), B rows [waveC*64,+64)
    // 8 global_load_lds calls of 1KB each per step (4 A-chunks + 4 B-chunks).
    auto STAGE = [&](int buf, int k0) {
#pragma unroll
        for (int c = 0; c < 4; ++c) {
            int byteoff = c * 1024 + lane * 16;   // within the 4KB half
            int r  = byteoff >> 6;                // 64B per row -> local row 0..63
            int kk = (byteoff & 63) >> 1;         // bf16 index within row
            const ushort* gA = Xb + (size_t)(rowBase + waveR * 64 + r) * D + k0 + kk;
            const ushort* gB = Xb + (size_t)(colBase + waveC * 64 + r) * D + k0 + kk;
            __builtin_amdgcn_global_load_lds(GLB_PTR(gA), LDS_PTR(&As[wave][buf][c * 512]), 16, 0, 0);
            __builtin_amdgcn_global_load_lds(GLB_PTR(gB), LDS_PTR(&Bs[wave][buf][c * 512]), 16, 0, 0);
        }
    };

    int nt = D / GBK;   // 32
    STAGE(0, 0);
    STAGE(1, GBK);

    int cur = 0;
    for (int t = 0; t < nt; ++t) {
        // wait for step t's 8 loads (step t+1's 8 may stay in flight)
        if (t < nt - 1) {
            asm volatile("s_waitcnt vmcnt(8)" ::: "memory");
        } else {
            asm volatile("s_waitcnt vmcnt(0)" ::: "memory");
        }
        __builtin_amdgcn_sched_barrier(0);

        bf16x8 aF[4], bF[4];
        int chunk = (lane >> 4) * 8;
        const ushort* aB = &As[wave][cur][0];
        const ushort* bB = &Bs[wave][cur][0];
#pragma unroll
        for (int m = 0; m < 4; ++m) {
            int rl = m * 16 + (lane & 15);
            aF[m] = *reinterpret_cast<const bf16x8*>(&aB[rl * GBK + chunk]);
            bF[m] = *reinterpret_cast<const bf16x8*>(&bB[rl * GBK + chunk]);
        }
#pragma unroll
        for (int m = 0; m < 4; ++m)
#pragma unroll
            for (int n2 = 0; n2 < 4; ++n2)
                acc[m][n2] = __builtin_amdgcn_mfma_f32_16x16x32_bf16(aF[m], bF[n2], acc[m][n2], 0, 0, 0);

        if (t + 2 < nt) STAGE(cur, (t + 2) * GBK);   // overwrite just-consumed buf
        cur ^= 1;
    }

    __syncthreads();   // tlist shared across waves from here on

    // epilogue: ballot-compact candidates into LDS tile list (no global atomics)
    int cr = (lane >> 4) * 4;
    int cc = lane & 15;
    unsigned long long lmask_lt = (1ull << lane) - 1ull;
#pragma unroll
    for (int m = 0; m < 4; ++m) {
#pragma unroll
        for (int n2 = 0; n2 < 4; ++n2) {
            int gcol = colBase + waveC * 64 + n2 * 16 + cc;
            float sqc = sq[gcol];
#pragma unroll
            for (int r = 0; r < 4; ++r) {
                int grow = rowBase + waveR * 64 + m * 16 + cr + r;
                float v = sq[grow] + sqc - 2.0f * acc[m][n2][r];
                bool pred = (v < P0SQ) && (grow != gcol);
                unsigned long long mask = __ballot(pred);
                if (mask) {
                    int leader = __ffsll((long long)mask) - 1;
                    int tot = __popcll(mask);
                    int base = 0;
                    if (lane == leader) base = atomicAdd(&s_cnt, tot);
                    base = __shfl(base, leader);
                    if (pred) {
                        int idx = base + __popcll(mask & lmask_lt);
                        if (idx < TCAP) {
                            float d = sqrtf(fmaxf(v, 1e-12f));
                            uint32_t pk = ((uint32_t)grow << 12) | (uint32_t)gcol;
                            float2 e; e.x = d; e.y = __builtin_bit_cast(float, pk);
                            tlist[idx] = e;
                        }
                    }
                }
            }
        }
    }
    __syncthreads();

    int cnt = s_cnt;
    int wr = min(cnt, TCAP);
    for (int e = tid; e < wr; e += 256)
        tileList[(size_t)wgid * TCAP + e] = tlist[e];
    if (tid == 0) tileCnt[wgid] = cnt;
    if (cnt > TCAP && tid < GBM)   // astronomically unlikely; rows lose records
        needFB[rowBase + tid] = 1;
}

// ---------------------------------------------------------------------------
// Kernel 3: binning — scatter tile lists into per-row candidate lists.
// ---------------------------------------------------------------------------
__global__ __launch_bounds__(256) void bin_kernel(const float2* __restrict__ tileList,
                                                  const int* __restrict__ tileCnt,
                                                  float2* __restrict__ cand,
                                                  int* __restrict__ cntArr) {
    int t = blockIdx.x;
    int cnt = min(tileCnt[t], TCAP);
    for (int e = threadIdx.x; e < cnt; e += 256) {
        float2 v = tileList[(size_t)t * TCAP + e];
        uint32_t pk = __builtin_bit_cast(uint32_t, v.y);
        int i = (int)(pk >> 12), j = (int)(pk & 4095u);
        int p = atomicAdd(&cntArr[i], 1);
        if (p < CAP) {
            float2 e1; e1.x = v.x; e1.y = __builtin_bit_cast(float, j);
            cand[(size_t)i * CAP + p] = e1;
        }
    }
}

// ---------------------------------------------------------------------------
// Kernel 4: per-row finalize from candidate lists. One WAVE per row (4/block).
// ---------------------------------------------------------------------------
__global__ __launch_bounds__(256) void rowfinal_kernel(const float2* __restrict__ cand,
                                                       const int* __restrict__ cntArr,
                                                       const int* __restrict__ targets,
                                                       const ushort* __restrict__ Xb,
                                                       const float* __restrict__ sq,
                                                       const int* __restrict__ f1,
                                                       const int* __restrict__ f2,
                                                       const int* __restrict__ lcnt,
                                                       int* __restrict__ needFB,
                                                       float* __restrict__ rowLoss,
                                                       int N, int D) {
    __shared__ float dbuf[4][CAP];
    int tid = threadIdx.x, lane = tid & 63, w = tid >> 6;
    int row = blockIdx.x * 4 + w;
    int ti = targets[row];
    int lc = lcnt[ti];
    bool validRow = (lc >= 2) && (lc < N);
    int cnt = cntArr[row];
    bool fb = (cnt < KSEL + 1) || (cnt > CAP);
    int lim = fb ? 0 : cnt;

    float ed[4]; int ej[4];
#pragma unroll
    for (int s = 0; s < 4; ++s) {
        int idx = lane + s * 64;
        bool in = (!fb) && (idx < cnt);
        if (in) {
            float2 e = cand[(size_t)row * CAP + idx];
            ed[s] = e.x; ej[s] = __builtin_bit_cast(int, e.y);
            dbuf[w][idx] = e.x;
        } else { ed[s] = BIGV; ej[s] = -1; }
    }
    __syncthreads();

    // exact rank: thr = value at rank KSEL (0-based) among candidates
    int rlo[4] = {0, 0, 0, 0}, req[4] = {0, 0, 0, 0};
    for (int q = 0; q < lim; ++q) {
        float u = dbuf[w][q];
#pragma unroll
        for (int s = 0; s < 4; ++s) {
            rlo[s] += (u < ed[s]);
            req[s] += (u == ed[s]);
        }
    }
    float thrc = BIGV;
#pragma unroll
    for (int s = 0; s < 4; ++s)
        if (ej[s] >= 0 && rlo[s] <= KSEL && KSEL < rlo[s] + req[s]) thrc = fminf(thrc, ed[s]);
    for (int off = 32; off; off >>= 1) thrc = fminf(thrc, __shfl_down(thrc, off));
    float thr = __shfl(thrc, 0);

    // masked sums over candidates (below-thr set fully contained in list)
    float posS = 0.f, negS = 0.f;
    int apb = 0;
#pragma unroll
    for (int s = 0; s < 4; ++s) {
        if (ej[s] >= 0 && ed[s] < thr) {
            bool same = (targets[ej[s]] == ti);
            float e = expf(ALPHA * (1.0f - ed[s]));
            if (same) { posS += e; apb = 1; }
            else negS += e;
        }
    }
    for (int off = 32; off; off >>= 1) {
        posS += __shfl_down(posS, off);
        negS += __shfl_down(negS, off);
        apb = max(apb, __shfl_down(apb, off));
    }

    // first-positive fallback distance (bf16 dot, fp32 accum)
    int fp = 0;
    float dot = 0.f;
    if (validRow) {
        fp = (row == f1[ti]) ? f2[ti] : f1[ti];
        const ushort* xr = Xb + (size_t)row * D;
        const ushort* xf = Xb + (size_t)fp * D;
        for (int c = lane; c < D / 4; c += 64) {
            ushort4 a = *reinterpret_cast<const ushort4*>(xr + (size_t)c * 4);
            ushort4 b = *reinterpret_cast<const ushort4*>(xf + (size_t)c * 4);
            dot += bfval(a.x) * bfval(b.x) + bfval(a.y) * bfval(b.y)
                 + bfval(a.z) * bfval(b.z) + bfval(a.w) * bfval(b.w);
        }
    }
    for (int off = 32; off; off >>= 1) dot += __shfl_down(dot, off);

    if (lane == 0) {
        if (fb) {
            needFB[row] = 1;
        } else if (!validRow) {
            rowLoss[row] = BIGV;
        } else {
            float fbD = sqrtf(fmaxf(sq[row] + sq[fp] - 2.0f * dot, 1e-12f));
            float posLogit = apb ? posS : expf(ALPHA * (1.0f - fbD));
            rowLoss[row] = -logf(posLogit / (posLogit + negS));
        }
    }
}

// ---------------------------------------------------------------------------
// Kernel 5: exact fallback (full-row recompute). Expected zero work.
// ---------------------------------------------------------------------------
__global__ __launch_bounds__(256) void fallback_kernel(const ushort* __restrict__ Xb,
                                                       const float* __restrict__ sq,
                                                       const int* __restrict__ targets,
                                                       const int* __restrict__ needFB,
                                                       const int* __restrict__ f1,
                                                       const int* __restrict__ f2,
                                                       const int* __restrict__ lcnt,
                                                       float* __restrict__ rowLoss,
                                                       int N, int D) {
    int row = blockIdx.x;
    if (!needFB[row]) return;

    __shared__ float xrow[1024];
    __shared__ float rowD[NMAX];
    __shared__ float sF[4];
    __shared__ int sI[4];
    int tid = threadIdx.x;

    for (int k = tid; k < D; k += 256) xrow[k] = bfval(Xb[(size_t)row * D + k]);
    __syncthreads();

    for (int j = tid; j < N; j += 256) {
        float dot = 0.f;
        const ushort* xj = Xb + (size_t)j * D;
        for (int k = 0; k < D; ++k) dot += xrow[k] * bfval(xj[k]);
        rowD[j] = (j == row) ? BIGV
                             : sqrtf(fmaxf(sq[row] + sq[j] - 2.0f * dot, 1e-12f));
    }
    __syncthreads();

    uint32_t lo = 0, hi = 0x40800000u;
    while (lo < hi) {
        uint32_t mid = (lo + hi) >> 1;
        float mv = __builtin_bit_cast(float, mid);
        int c = 0;
        for (int j = tid; j < N; j += 256) c += (rowD[j] <= mv);
        c = blockReduceSumI(c, sI);
        if (c >= KSEL + 1) hi = mid; else lo = mid + 1;
    }
    float thr = __builtin_bit_cast(float, hi);

    int ti = targets[row];
    int lc = lcnt[ti];
    bool validRow = (lc >= 2) && (lc < N);

    float posS = 0.f, negS = 0.f;
    int apb = 0;
    for (int j = tid; j < N; j += 256) {
        if (j == row) continue;
        float d = rowD[j];
        bool same = (targets[j] == ti);
        if (d < thr) {
            float e = expf(ALPHA * (1.0f - d));
            if (same) { posS += e; apb = 1; }
            else negS += e;
        }
    }
    posS = blockReduceSumF(posS, sF);
    negS = blockReduceSumF(negS, sF);
    apb = blockReduceMaxI(apb, sI);

    if (tid == 0) {
        if (!validRow) { rowLoss[row] = BIGV; return; }
        int fp = (row == f1[ti]) ? f2[ti] : f1[ti];
        float posLogit = apb ? posS : expf(ALPHA * (1.0f - rowD[fp]));
        rowLoss[row] = -logf(posLogit / (posLogit + negS));
    }
}

// ---------------------------------------------------------------------------
// Kernel 6: single-block reduction over rowLoss -> out[4]
// ---------------------------------------------------------------------------
__global__ __launch_bounds__(256) void reduce_kernel(const float* __restrict__ rowLoss,
                                                     float* __restrict__ out, int N) {
    __shared__ float sF[4];
    __shared__ int sI[4];
    int tid = threadIdx.x;
    float sumL = 0.f;
    int nValid = 0, nAcc = 0;
    for (int j = tid; j < N; j += 256) {
        float L = rowLoss[j];
        if (L != BIGV) {
            sumL += L;
            ++nValid;
            if (L < 0.6f) ++nAcc;
        }
    }
    sumL = blockReduceSumF(sumL, sF);
    nValid = blockReduceSumI(nValid, sI);
    nAcc = blockReduceSumI(nAcc, sI);
    if (tid == 0) {
        out[0] = (nValid > 0) ? sumL / (float)nValid : 0.f;
        out[1] = (float)nAcc / (float)N;
        out[2] = 0.f;
        out[3] = 0.f;
    }
}

// ---------------------------------------------------------------------------
extern "C" void kernel_launch(void* const* d_in, const int* in_sizes, int n_in,
                              void* d_out, int out_size, void* d_ws, size_t ws_size,
                              hipStream_t stream) {
    const float* X = (const float*)d_in[0];
    const int* targets = (const int*)d_in[1];
    float* out = (float*)d_out;

    int N = in_sizes[1];             // 4096
    int D = in_sizes[0] / N;         // 1024
    int tiles = N / GBM;             // 32
    int nTiles = tiles * tiles;      // 1024

    // 8B-aligned float2 arrays first
    float2* cand     = (float2*)d_ws;                          // N*CAP f2      (7.3 MB)
    float2* tileList = cand + (size_t)N * CAP;                 // nTiles*TCAP   (7.3 MB)
    float*  sq       = (float*)(tileList + (size_t)nTiles * TCAP);
    float*  rowLoss  = sq + N;
    int*    cntArr   = (int*)(rowLoss + N);
    int*    needFB   = cntArr + N;
    int*    tileCnt  = needFB + N;                             // nTiles i32
    int*    f1       = tileCnt + nTiles;
    int*    f2       = f1 + 64;
    int*    lcnt     = f2 + 64;
    ushort* Xb       = (ushort*)(lcnt + 64 + 64);              // N*D bf16 (8 MB)

    hipMemsetAsync(cntArr, 0, N * sizeof(int), stream);
    hipMemsetAsync(needFB, 0, N * sizeof(int), stream);

    prep_kernel<<<N + 64, 256, 0, stream>>>(X, Xb, sq, targets, f1, f2, lcnt, D, N);

    distgemm_mfma<<<nTiles, 256, 0, stream>>>(Xb, sq, tileList, tileCnt, needFB, N, D);

    bin_kernel<<<nTiles, 256, 0, stream>>>(tileList, tileCnt, cand, cntArr);

    rowfinal_kernel<<<N / 4, 256, 0, stream>>>(cand, cntArr, targets, Xb, sq,
                                               f1, f2, lcnt, needFB, rowLoss, N, D);

    fallback_kernel<<<N, 256, 0, stream>>>(Xb, sq, targets, needFB,
                                           f1, f2, lcnt, rowLoss, N, D);

    reduce_kernel<<<1, 256, 0, stream>>>(rowLoss, out, N);
}

// Round 11
// 139.833 us; speedup vs baseline: 1.0927x; 1.0927x over previous
//
#include <hip/hip_runtime.h>
#include <hip/hip_bf16.h>
#include <cfloat>
#include <climits>
#include <cstdint>

#define ALPHA 30.0f
#define KSEL 16          // threshold = sorted[:,16] (17th smallest off-diag)
#define P0 1.368f        // candidate cutoff: E[cnt/row]≈82, P(cnt<17)~1e-13
#define P0SQ (P0 * P0)
#define CAP 224          // per-row candidate capacity (mean 82, +15 sigma)
#define TCAP 896         // per-tile candidate capacity (mean 330, +31 sigma)
#define BIGV 1e30f
#define NMAX 4096

typedef __attribute__((ext_vector_type(8))) short bf16x8;
typedef __attribute__((ext_vector_type(4))) float f32x4;

#define LDS_PTR(p) ((__attribute__((address_space(3))) uint32_t*)(p))
#define GLB_PTR(p) ((const __attribute__((address_space(1))) uint32_t*)(p))

__device__ inline float bfval(ushort u) {
    return __builtin_bit_cast(float, (uint32_t)u << 16);
}

// ---------------------------------------------------------------------------
// block reduce helpers (256 threads, 4 waves)
// ---------------------------------------------------------------------------
__device__ inline float blockReduceSumF(float v, float* s) {
    for (int off = 32; off; off >>= 1) v += __shfl_down(v, off);
    int tid = threadIdx.x, wid = tid >> 6;
    if ((tid & 63) == 0) s[wid] = v;
    __syncthreads();
    float r;
    if (tid == 0) { r = s[0] + s[1] + s[2] + s[3]; s[0] = r; }
    __syncthreads();
    r = s[0];
    __syncthreads();
    return r;
}

__device__ inline int blockReduceSumI(int v, int* s) {
    for (int off = 32; off; off >>= 1) v += __shfl_down(v, off);
    int tid = threadIdx.x, wid = tid >> 6;
    if ((tid & 63) == 0) s[wid] = v;
    __syncthreads();
    int r;
    if (tid == 0) { r = s[0] + s[1] + s[2] + s[3]; s[0] = r; }
    __syncthreads();
    r = s[0];
    __syncthreads();
    return r;
}

__device__ inline int blockReduceMaxI(int v, int* s) {
    for (int off = 32; off; off >>= 1) v = max(v, __shfl_down(v, off));
    int tid = threadIdx.x, wid = tid >> 6;
    if ((tid & 63) == 0) s[wid] = v;
    __syncthreads();
    int r;
    if (tid == 0) { r = max(max(s[0], s[1]), max(s[2], s[3])); s[0] = r; }
    __syncthreads();
    r = s[0];
    __syncthreads();
    return r;
}

// ---------------------------------------------------------------------------
// Kernel 1: fused fp32->bf16 (RNE) + row sq-norm; blocks >= N do labelinfo.
// ---------------------------------------------------------------------------
__global__ __launch_bounds__(256) void prep_kernel(const float* __restrict__ X,
                                                   ushort* __restrict__ Xb,
                                                   float* __restrict__ sq,
                                                   const int* __restrict__ targets,
                                                   int* __restrict__ f1,
                                                   int* __restrict__ f2,
                                                   int* __restrict__ lcnt,
                                                   int D, int N) {
    __shared__ float sw[4];
    __shared__ int s1[4], s2[4], sc[4];
    int tid = threadIdx.x;
    int wid = tid >> 6;

    if (blockIdx.x >= (unsigned)N) {
        // ---- labelinfo: per-label two smallest indices + count ----
        int lbl = blockIdx.x - N;
        int a1 = INT_MAX, a2 = INT_MAX, c = 0;
        for (int j = tid; j < N; j += 256) {
            if (targets[j] == lbl) {
                ++c;
                if (j < a1) { a2 = a1; a1 = j; }
                else if (j < a2) a2 = j;
            }
        }
        for (int off = 32; off; off >>= 1) {
            int b1 = __shfl_down(a1, off), b2 = __shfl_down(a2, off), bc = __shfl_down(c, off);
            int m1 = min(a1, b1);
            int m2 = min(max(a1, b1), min(a2, b2));
            a1 = m1; a2 = m2; c += bc;
        }
        if ((tid & 63) == 0) { s1[wid] = a1; s2[wid] = a2; sc[wid] = c; }
        __syncthreads();
        if (tid == 0) {
            int r1 = s1[0], r2 = s2[0], rc = sc[0];
            for (int w = 1; w < 4; ++w) {
                int m1 = min(r1, s1[w]);
                int m2 = min(max(r1, s1[w]), min(r2, s2[w]));
                r1 = m1; r2 = m2; rc += sc[w];
            }
            f1[lbl] = r1; f2[lbl] = r2; lcnt[lbl] = rc;
        }
        return;
    }

    int row = blockIdx.x;
    const float4* xr = reinterpret_cast<const float4*>(X + (size_t)row * D);
    ushort4* xo = reinterpret_cast<ushort4*>(Xb + (size_t)row * D);
    float s = 0.f;
    for (int c = tid; c < D / 4; c += 256) {
        float4 v = xr[c];
        s += v.x * v.x + v.y * v.y + v.z * v.z + v.w * v.w;
        ushort4 o;
        uint32_t b;
        b = __builtin_bit_cast(uint32_t, v.x); o.x = (ushort)((b + 0x7FFF + ((b >> 16) & 1)) >> 16);
        b = __builtin_bit_cast(uint32_t, v.y); o.y = (ushort)((b + 0x7FFF + ((b >> 16) & 1)) >> 16);
        b = __builtin_bit_cast(uint32_t, v.z); o.z = (ushort)((b + 0x7FFF + ((b >> 16) & 1)) >> 16);
        b = __builtin_bit_cast(uint32_t, v.w); o.w = (ushort)((b + 0x7FFF + ((b >> 16) & 1)) >> 16);
        xo[c] = o;
    }
    for (int off = 32; off; off >>= 1) s += __shfl_down(s, off);
    if ((tid & 63) == 0) sw[wid] = s;
    __syncthreads();
    if (tid == 0) sq[row] = sw[0] + sw[1] + sw[2] + sw[3];
}

// ---------------------------------------------------------------------------
// Kernel 2: bf16 MFMA GEMM, BK=64 (128 B LDS rows) with T2 XOR-swizzle.
// LDS layout: As[row][kbyte ^ ((row&7)<<4)] — within-row permutation.
// global_load_lds keeps the LDS dest LINEAR; the inverse swizzle is applied
// to the GLOBAL source (16B-granule permutation inside each 128B window,
// coalescing preserved). Fragment ds_read_b128 slots become chunk^(lane&7)
// -> 2-way bank access (free) instead of 8-way.
// Candidates (v < P0^2, off-diag) ballot-compacted to LDS, bulk-written.
// ---------------------------------------------------------------------------
#define GBM 128
#define GBK 64
__global__ __launch_bounds__(256) void distgemm_mfma(const ushort* __restrict__ Xb,
                                                     const float* __restrict__ sq,
                                                     float2* __restrict__ tileList,
                                                     int* __restrict__ tileCnt,
                                                     int* __restrict__ needFB,
                                                     int N, int D) {
    __shared__ ushort As[GBM * GBK];   // 16 KB
    __shared__ ushort Bs[GBM * GBK];   // 16 KB
    __shared__ float2 tlist[TCAP];     // 7 KB
    __shared__ int s_cnt;

    // XCD-aware swizzle: 1024 blocks, 8 XCDs -> contiguous row-panels per XCD.
    int wg = blockIdx.x;
    int wgid = (wg & 7) * 128 + (wg >> 3);
    int by = wgid >> 5, bx = wgid & 31;

    int tid = threadIdx.x;
    int lane = tid & 63;
    int wave = tid >> 6;
    int waveR = wave >> 1;
    int waveC = wave & 1;

    int rowBase = by * GBM;
    int colBase = bx * GBM;

    if (tid == 0) s_cnt = 0;

    f32x4 acc[4][4];
#pragma unroll
    for (int m = 0; m < 4; ++m)
#pragma unroll
        for (int n2 = 0; n2 < 4; ++n2) {
            f32x4 z = {0.f, 0.f, 0.f, 0.f};
            acc[m][n2] = z;
        }

    // staging: 16 chunks of 1KB per tile (A and B); wave w does chunks [4w,4w+4)
    // physical dest P = c*1024 + lane*16 -> row r = c*8 + (lane>>3),
    // within-row byte w0 = (lane&7)*16; logical col-byte = w0 ^ ((r&7)<<4).
    auto STAGE = [&](int k0) {
#pragma unroll
        for (int p = 0; p < 4; ++p) {
            int c = wave * 4 + p;                     // 0..15
            int r = c * 8 + (lane >> 3);              // 0..127
            int cb = ((lane & 7) * 16) ^ ((r & 7) << 4);
            const ushort* gA = Xb + (size_t)(rowBase + r) * D + k0 + (cb >> 1);
            const ushort* gB = Xb + (size_t)(colBase + r) * D + k0 + (cb >> 1);
            __builtin_amdgcn_global_load_lds(GLB_PTR(gA), LDS_PTR(As + c * 512), 16, 0, 0);
            __builtin_amdgcn_global_load_lds(GLB_PTR(gB), LDS_PTR(Bs + c * 512), 16, 0, 0);
        }
    };

    const char* AsB = (const char*)As;
    const char* BsB = (const char*)Bs;
    int nt = D / GBK;   // 16
    for (int t = 0; t < nt; ++t) {
        STAGE(t * GBK);
        __syncthreads();   // tile staged (drains vmcnt)

        int hi = lane >> 4;            // 0..3
        int l15 = lane & 15;
#pragma unroll
        for (int kk = 0; kk < 2; ++kk) {
            int colb = (kk * 4 + hi) * 16;
            bf16x8 aF[4], bF[4];
#pragma unroll
            for (int m = 0; m < 4; ++m) {
                int arl = waveR * 64 + m * 16 + l15;
                int brl = waveC * 64 + m * 16 + l15;
                aF[m] = *reinterpret_cast<const bf16x8*>(AsB + arl * 128 + (colb ^ ((arl & 7) << 4)));
                bF[m] = *reinterpret_cast<const bf16x8*>(BsB + brl * 128 + (colb ^ ((brl & 7) << 4)));
            }
#pragma unroll
            for (int m = 0; m < 4; ++m)
#pragma unroll
                for (int n2 = 0; n2 < 4; ++n2)
                    acc[m][n2] = __builtin_amdgcn_mfma_f32_16x16x32_bf16(aF[m], bF[n2], acc[m][n2], 0, 0, 0);
        }
        __syncthreads();   // all waves done reading before next overwrite
    }

    // epilogue: ballot-compact candidates into LDS tile list (no global atomics)
    int cr = (lane >> 4) * 4;
    int cc = lane & 15;
    unsigned long long lmask_lt = (1ull << lane) - 1ull;
#pragma unroll
    for (int m = 0; m < 4; ++m) {
#pragma unroll
        for (int n2 = 0; n2 < 4; ++n2) {
            int gcol = colBase + waveC * 64 + n2 * 16 + cc;
            float sqc = sq[gcol];
#pragma unroll
            for (int r = 0; r < 4; ++r) {
                int grow = rowBase + waveR * 64 + m * 16 + cr + r;
                float v = sq[grow] + sqc - 2.0f * acc[m][n2][r];
                bool pred = (v < P0SQ) && (grow != gcol);
                unsigned long long mask = __ballot(pred);
                if (mask) {
                    int leader = __ffsll((long long)mask) - 1;
                    int tot = __popcll(mask);
                    int base = 0;
                    if (lane == leader) base = atomicAdd(&s_cnt, tot);
                    base = __shfl(base, leader);
                    if (pred) {
                        int idx = base + __popcll(mask & lmask_lt);
                        if (idx < TCAP) {
                            float d = sqrtf(fmaxf(v, 1e-12f));
                            uint32_t pk = ((uint32_t)grow << 12) | (uint32_t)gcol;
                            float2 e; e.x = d; e.y = __builtin_bit_cast(float, pk);
                            tlist[idx] = e;
                        }
                    }
                }
            }
        }
    }
    __syncthreads();

    int cnt = s_cnt;
    int wr = min(cnt, TCAP);
    for (int e = tid; e < wr; e += 256)
        tileList[(size_t)wgid * TCAP + e] = tlist[e];
    if (tid == 0) tileCnt[wgid] = cnt;
    if (cnt > TCAP && tid < GBM)   // astronomically unlikely; rows lose records
        needFB[rowBase + tid] = 1;
}

// ---------------------------------------------------------------------------
// Kernel 3: binning — scatter tile lists into per-row candidate lists.
// ---------------------------------------------------------------------------
__global__ __launch_bounds__(256) void bin_kernel(const float2* __restrict__ tileList,
                                                  const int* __restrict__ tileCnt,
                                                  float2* __restrict__ cand,
                                                  int* __restrict__ cntArr) {
    int t = blockIdx.x;
    int cnt = min(tileCnt[t], TCAP);
    for (int e = threadIdx.x; e < cnt; e += 256) {
        float2 v = tileList[(size_t)t * TCAP + e];
        uint32_t pk = __builtin_bit_cast(uint32_t, v.y);
        int i = (int)(pk >> 12), j = (int)(pk & 4095u);
        int p = atomicAdd(&cntArr[i], 1);
        if (p < CAP) {
            float2 e1; e1.x = v.x; e1.y = __builtin_bit_cast(float, j);
            cand[(size_t)i * CAP + p] = e1;
        }
    }
}

// ---------------------------------------------------------------------------
// Kernel 4: per-row finalize from candidate lists. One WAVE per row (4/block).
// ---------------------------------------------------------------------------
__global__ __launch_bounds__(256) void rowfinal_kernel(const float2* __restrict__ cand,
                                                       const int* __restrict__ cntArr,
                                                       const int* __restrict__ targets,
                                                       const ushort* __restrict__ Xb,
                                                       const float* __restrict__ sq,
                                                       const int* __restrict__ f1,
                                                       const int* __restrict__ f2,
                                                       const int* __restrict__ lcnt,
                                                       int* __restrict__ needFB,
                                                       float* __restrict__ rowLoss,
                                                       int N, int D) {
    __shared__ float dbuf[4][CAP];
    int tid = threadIdx.x, lane = tid & 63, w = tid >> 6;
    int row = blockIdx.x * 4 + w;
    int ti = targets[row];
    int lc = lcnt[ti];
    bool validRow = (lc >= 2) && (lc < N);
    int cnt = cntArr[row];
    bool fb = (cnt < KSEL + 1) || (cnt > CAP);
    int lim = fb ? 0 : cnt;

    float ed[4]; int ej[4];
#pragma unroll
    for (int s = 0; s < 4; ++s) {
        int idx = lane + s * 64;
        bool in = (!fb) && (idx < cnt);
        if (in) {
            float2 e = cand[(size_t)row * CAP + idx];
            ed[s] = e.x; ej[s] = __builtin_bit_cast(int, e.y);
            dbuf[w][idx] = e.x;
        } else { ed[s] = BIGV; ej[s] = -1; }
    }
    __syncthreads();

    // exact rank: thr = value at rank KSEL (0-based) among candidates
    int rlo[4] = {0, 0, 0, 0}, req[4] = {0, 0, 0, 0};
    for (int q = 0; q < lim; ++q) {
        float u = dbuf[w][q];
#pragma unroll
        for (int s = 0; s < 4; ++s) {
            rlo[s] += (u < ed[s]);
            req[s] += (u == ed[s]);
        }
    }
    float thrc = BIGV;
#pragma unroll
    for (int s = 0; s < 4; ++s)
        if (ej[s] >= 0 && rlo[s] <= KSEL && KSEL < rlo[s] + req[s]) thrc = fminf(thrc, ed[s]);
    for (int off = 32; off; off >>= 1) thrc = fminf(thrc, __shfl_down(thrc, off));
    float thr = __shfl(thrc, 0);

    // masked sums over candidates (below-thr set fully contained in list)
    float posS = 0.f, negS = 0.f;
    int apb = 0;
#pragma unroll
    for (int s = 0; s < 4; ++s) {
        if (ej[s] >= 0 && ed[s] < thr) {
            bool same = (targets[ej[s]] == ti);
            float e = expf(ALPHA * (1.0f - ed[s]));
            if (same) { posS += e; apb = 1; }
            else negS += e;
        }
    }
    for (int off = 32; off; off >>= 1) {
        posS += __shfl_down(posS, off);
        negS += __shfl_down(negS, off);
        apb = max(apb, __shfl_down(apb, off));
    }

    // first-positive fallback distance (bf16 dot, fp32 accum)
    int fp = 0;
    float dot = 0.f;
    if (validRow) {
        fp = (row == f1[ti]) ? f2[ti] : f1[ti];
        const ushort* xr = Xb + (size_t)row * D;
        const ushort* xf = Xb + (size_t)fp * D;
        for (int c = lane; c < D / 4; c += 64) {
            ushort4 a = *reinterpret_cast<const ushort4*>(xr + (size_t)c * 4);
            ushort4 b = *reinterpret_cast<const ushort4*>(xf + (size_t)c * 4);
            dot += bfval(a.x) * bfval(b.x) + bfval(a.y) * bfval(b.y)
                 + bfval(a.z) * bfval(b.z) + bfval(a.w) * bfval(b.w);
        }
    }
    for (int off = 32; off; off >>= 1) dot += __shfl_down(dot, off);

    if (lane == 0) {
        if (fb) {
            needFB[row] = 1;
        } else if (!validRow) {
            rowLoss[row] = BIGV;
        } else {
            float fbD = sqrtf(fmaxf(sq[row] + sq[fp] - 2.0f * dot, 1e-12f));
            float posLogit = apb ? posS : expf(ALPHA * (1.0f - fbD));
            rowLoss[row] = -logf(posLogit / (posLogit + negS));
        }
    }
}

// ---------------------------------------------------------------------------
// Kernel 5: exact fallback (full-row recompute). Expected zero work.
// ---------------------------------------------------------------------------
__global__ __launch_bounds__(256) void fallback_kernel(const ushort* __restrict__ Xb,
                                                       const float* __restrict__ sq,
                                                       const int* __restrict__ targets,
                                                       const int* __restrict__ needFB,
                                                       const int* __restrict__ f1,
                                                       const int* __restrict__ f2,
                                                       const int* __restrict__ lcnt,
                                                       float* __restrict__ rowLoss,
                                                       int N, int D) {
    int row = blockIdx.x;
    if (!needFB[row]) return;

    __shared__ float xrow[1024];
    __shared__ float rowD[NMAX];
    __shared__ float sF[4];
    __shared__ int sI[4];
    int tid = threadIdx.x;

    for (int k = tid; k < D; k += 256) xrow[k] = bfval(Xb[(size_t)row * D + k]);
    __syncthreads();

    for (int j = tid; j < N; j += 256) {
        float dot = 0.f;
        const ushort* xj = Xb + (size_t)j * D;
        for (int k = 0; k < D; ++k) dot += xrow[k] * bfval(xj[k]);
        rowD[j] = (j == row) ? BIGV
                             : sqrtf(fmaxf(sq[row] + sq[j] - 2.0f * dot, 1e-12f));
    }
    __syncthreads();

    uint32_t lo = 0, hi = 0x40800000u;
    while (lo < hi) {
        uint32_t mid = (lo + hi) >> 1;
        float mv = __builtin_bit_cast(float, mid);
        int c = 0;
        for (int j = tid; j < N; j += 256) c += (rowD[j] <= mv);
        c = blockReduceSumI(c, sI);
        if (c >= KSEL + 1) hi = mid; else lo = mid + 1;
    }
    float thr = __builtin_bit_cast(float, hi);

    int ti = targets[row];
    int lc = lcnt[ti];
    bool validRow = (lc >= 2) && (lc < N);

    float posS = 0.f, negS = 0.f;
    int apb = 0;
    for (int j = tid; j < N; j += 256) {
        if (j == row) continue;
        float d = rowD[j];
        bool same = (targets[j] == ti);
        if (d < thr) {
            float e = expf(ALPHA * (1.0f - d));
            if (same) { posS += e; apb = 1; }
            else negS += e;
        }
    }
    posS = blockReduceSumF(posS, sF);
    negS = blockReduceSumF(negS, sF);
    apb = blockReduceMaxI(apb, sI);

    if (tid == 0) {
        if (!validRow) { rowLoss[row] = BIGV; return; }
        int fp = (row == f1[ti]) ? f2[ti] : f1[ti];
        float posLogit = apb ? posS : expf(ALPHA * (1.0f - rowD[fp]));
        rowLoss[row] = -logf(posLogit / (posLogit + negS));
    }
}

// ---------------------------------------------------------------------------
// Kernel 6: single-block reduction over rowLoss -> out[4]
// ---------------------------------------------------------------------------
__global__ __launch_bounds__(256) void reduce_kernel(const float* __restrict__ rowLoss,
                                                     float* __restrict__ out, int N) {
    __shared__ float sF[4];
    __shared__ int sI[4];
    int tid = threadIdx.x;
    float sumL = 0.f;
    int nValid = 0, nAcc = 0;
    for (int j = tid; j < N; j += 256) {
        float L = rowLoss[j];
        if (L != BIGV) {
            sumL += L;
            ++nValid;
            if (L < 0.6f) ++nAcc;
        }
    }
    sumL = blockReduceSumF(sumL, sF);
    nValid = blockReduceSumI(nValid, sI);
    nAcc = blockReduceSumI(nAcc, sI);
    if (tid == 0) {
        out[0] = (nValid > 0) ? sumL / (float)nValid : 0.f;
        out[1] = (float)nAcc / (float)N;
        out[2] = 0.f;
        out[3] = 0.f;
    }
}

// ---------------------------------------------------------------------------
extern "C" void kernel_launch(void* const* d_in, const int* in_sizes, int n_in,
                              void* d_out, int out_size, void* d_ws, size_t ws_size,
                              hipStream_t stream) {
    const float* X = (const float*)d_in[0];
    const int* targets = (const int*)d_in[1];
    float* out = (float*)d_out;

    int N = in_sizes[1];             // 4096
    int D = in_sizes[0] / N;         // 1024
    int tiles = N / GBM;             // 32
    int nTiles = tiles * tiles;      // 1024

    // 8B-aligned float2 arrays first
    float2* cand     = (float2*)d_ws;                          // N*CAP f2      (7.3 MB)
    float2* tileList = cand + (size_t)N * CAP;                 // nTiles*TCAP   (7.3 MB)
    float*  sq       = (float*)(tileList + (size_t)nTiles * TCAP);
    float*  rowLoss  = sq + N;
    int*    cntArr   = (int*)(rowLoss + N);
    int*    needFB   = cntArr + N;
    int*    tileCnt  = needFB + N;                             // nTiles i32
    int*    f1       = tileCnt + nTiles;
    int*    f2       = f1 + 64;
    int*    lcnt     = f2 + 64;
    ushort* Xb       = (ushort*)(lcnt + 64 + 64);              // N*D bf16 (8 MB)

    hipMemsetAsync(cntArr, 0, N * sizeof(int), stream);
    hipMemsetAsync(needFB, 0, N * sizeof(int), stream);

    prep_kernel<<<N + 64, 256, 0, stream>>>(X, Xb, sq, targets, f1, f2, lcnt, D, N);

    distgemm_mfma<<<nTiles, 256, 0, stream>>>(Xb, sq, tileList, tileCnt, needFB, N, D);

    bin_kernel<<<nTiles, 256, 0, stream>>>(tileList, tileCnt, cand, cntArr);

    rowfinal_kernel<<<N / 4, 256, 0, stream>>>(cand, cntArr, targets, Xb, sq,
                                               f1, f2, lcnt, needFB, rowLoss, N, D);

    fallback_kernel<<<N, 256, 0, stream>>>(Xb, sq, targets, needFB,
                                           f1, f2, lcnt, rowLoss, N, D);

    reduce_kernel<<<1, 256, 0, stream>>>(rowLoss, out, N);
}

// Round 12
// 133.087 us; speedup vs baseline: 1.1481x; 1.0507x over previous
//
#include <hip/hip_runtime.h>
#include <hip/hip_bf16.h>
#include <cfloat>
#include <climits>
#include <cstdint>

#define ALPHA 30.0f
#define KSEL 16          // threshold = sorted[:,16] (17th smallest off-diag)
#define P0 1.368f        // candidate cutoff: E[cnt/row]≈82, P(cnt<17)~1e-13
#define P0SQ (P0 * P0)
#define CAP 224          // per-row candidate capacity (mean 82, +15 sigma)
#define TCAP 1664        // per-tile candidate capacity (256² tile: mean 1310, +9.9 sigma)
#define BIGV 1e30f
#define NMAX 4096

typedef __attribute__((ext_vector_type(8))) short bf16x8;
typedef __attribute__((ext_vector_type(4))) float f32x4;

#define LDS_PTR(p) ((__attribute__((address_space(3))) uint32_t*)(p))
#define GLB_PTR(p) ((const __attribute__((address_space(1))) uint32_t*)(p))

__device__ inline float bfval(ushort u) {
    return __builtin_bit_cast(float, (uint32_t)u << 16);
}

// ---------------------------------------------------------------------------
// block reduce helpers (256 threads, 4 waves)
// ---------------------------------------------------------------------------
__device__ inline float blockReduceSumF(float v, float* s) {
    for (int off = 32; off; off >>= 1) v += __shfl_down(v, off);
    int tid = threadIdx.x, wid = tid >> 6;
    if ((tid & 63) == 0) s[wid] = v;
    __syncthreads();
    float r;
    if (tid == 0) { r = s[0] + s[1] + s[2] + s[3]; s[0] = r; }
    __syncthreads();
    r = s[0];
    __syncthreads();
    return r;
}

__device__ inline int blockReduceSumI(int v, int* s) {
    for (int off = 32; off; off >>= 1) v += __shfl_down(v, off);
    int tid = threadIdx.x, wid = tid >> 6;
    if ((tid & 63) == 0) s[wid] = v;
    __syncthreads();
    int r;
    if (tid == 0) { r = s[0] + s[1] + s[2] + s[3]; s[0] = r; }
    __syncthreads();
    r = s[0];
    __syncthreads();
    return r;
}

__device__ inline int blockReduceMaxI(int v, int* s) {
    for (int off = 32; off; off >>= 1) v = max(v, __shfl_down(v, off));
    int tid = threadIdx.x, wid = tid >> 6;
    if ((tid & 63) == 0) s[wid] = v;
    __syncthreads();
    int r;
    if (tid == 0) { r = max(max(s[0], s[1]), max(s[2], s[3])); s[0] = r; }
    __syncthreads();
    r = s[0];
    __syncthreads();
    return r;
}

// ---------------------------------------------------------------------------
// Kernel 1: fused fp32->bf16 (RNE) + row sq-norm; blocks >= N do labelinfo.
// ---------------------------------------------------------------------------
__global__ __launch_bounds__(256) void prep_kernel(const float* __restrict__ X,
                                                   ushort* __restrict__ Xb,
                                                   float* __restrict__ sq,
                                                   const int* __restrict__ targets,
                                                   int* __restrict__ f1,
                                                   int* __restrict__ f2,
                                                   int* __restrict__ lcnt,
                                                   int D, int N) {
    __shared__ float sw[4];
    __shared__ int s1[4], s2[4], sc[4];
    int tid = threadIdx.x;
    int wid = tid >> 6;

    if (blockIdx.x >= (unsigned)N) {
        int lbl = blockIdx.x - N;
        int a1 = INT_MAX, a2 = INT_MAX, c = 0;
        for (int j = tid; j < N; j += 256) {
            if (targets[j] == lbl) {
                ++c;
                if (j < a1) { a2 = a1; a1 = j; }
                else if (j < a2) a2 = j;
            }
        }
        for (int off = 32; off; off >>= 1) {
            int b1 = __shfl_down(a1, off), b2 = __shfl_down(a2, off), bc = __shfl_down(c, off);
            int m1 = min(a1, b1);
            int m2 = min(max(a1, b1), min(a2, b2));
            a1 = m1; a2 = m2; c += bc;
        }
        if ((tid & 63) == 0) { s1[wid] = a1; s2[wid] = a2; sc[wid] = c; }
        __syncthreads();
        if (tid == 0) {
            int r1 = s1[0], r2 = s2[0], rc = sc[0];
            for (int w = 1; w < 4; ++w) {
                int m1 = min(r1, s1[w]);
                int m2 = min(max(r1, s1[w]), min(r2, s2[w]));
                r1 = m1; r2 = m2; rc += sc[w];
            }
            f1[lbl] = r1; f2[lbl] = r2; lcnt[lbl] = rc;
        }
        return;
    }

    int row = blockIdx.x;
    const float4* xr = reinterpret_cast<const float4*>(X + (size_t)row * D);
    ushort4* xo = reinterpret_cast<ushort4*>(Xb + (size_t)row * D);
    float s = 0.f;
    for (int c = tid; c < D / 4; c += 256) {
        float4 v = xr[c];
        s += v.x * v.x + v.y * v.y + v.z * v.z + v.w * v.w;
        ushort4 o;
        uint32_t b;
        b = __builtin_bit_cast(uint32_t, v.x); o.x = (ushort)((b + 0x7FFF + ((b >> 16) & 1)) >> 16);
        b = __builtin_bit_cast(uint32_t, v.y); o.y = (ushort)((b + 0x7FFF + ((b >> 16) & 1)) >> 16);
        b = __builtin_bit_cast(uint32_t, v.z); o.z = (ushort)((b + 0x7FFF + ((b >> 16) & 1)) >> 16);
        b = __builtin_bit_cast(uint32_t, v.w); o.w = (ushort)((b + 0x7FFF + ((b >> 16) & 1)) >> 16);
        xo[c] = o;
    }
    for (int off = 32; off; off >>= 1) s += __shfl_down(s, off);
    if ((tid & 63) == 0) sw[wid] = s;
    __syncthreads();
    if (tid == 0) sq[row] = sw[0] + sw[1] + sw[2] + sw[3];
}

// ---------------------------------------------------------------------------
// Kernel 2: 256x256-tile bf16 MFMA GEMM, 8 waves (512 thr), ring-2 K-slots
// with COUNTED vmcnt (never 0 mid-loop) + raw s_barrier (no vmcnt(0) drain):
// loads for K-tile t+2 stay in flight across the whole of step t+1.
// T2 XOR-swizzle (proven R11: conflicts -> 0): LDS dest linear, inverse
// swizzle on global source, swizzled ds_read. Candidates ballot-compacted.
// ---------------------------------------------------------------------------
#define GBM 256
#define GBK 64
__global__ __launch_bounds__(512, 2) void distgemm_mfma(const ushort* __restrict__ Xb,
                                                        const float* __restrict__ sq,
                                                        float2* __restrict__ tileList,
                                                        int* __restrict__ tileCnt,
                                                        int* __restrict__ needFB,
                                                        int N, int D) {
    __shared__ ushort As[2][GBM * GBK];   // 2 x 32 KB
    __shared__ ushort Bs[2][GBM * GBK];   // 2 x 32 KB
    __shared__ float2 tlist[TCAP];        // 13 KB
    __shared__ int s_cnt;

    // XCD swizzle: 256 blocks, 8 XCDs -> 32 consecutive wgids per XCD.
    int wg = blockIdx.x;
    int wgid = (wg & 7) * 32 + (wg >> 3);
    int by = wgid >> 4, bx = wgid & 15;

    int tid = threadIdx.x;
    int lane = tid & 63;
    int wave = tid >> 6;        // 0..7
    int waveM = wave >> 2;      // 0..1  -> 128-row half
    int waveN = wave & 3;       // 0..3  -> 64-col quarter

    int rowBase = by * GBM;
    int colBase = bx * GBM;

    if (tid == 0) s_cnt = 0;

    f32x4 acc[8][4];
#pragma unroll
    for (int m = 0; m < 8; ++m)
#pragma unroll
        for (int n2 = 0; n2 < 4; ++n2) {
            f32x4 z = {0.f, 0.f, 0.f, 0.f};
            acc[m][n2] = z;
        }

    // staging: per K-tile, A(32KB)+B(32KB) = 8 loads/wave (4 rounds x {A,B}).
    // round p: rows [p*64, p*64+64); wave w covers rows p*64+w*8+(lane>>3).
    // phys within-row granule (lane&7); logical col byte = granule^((row&7)<<4);
    // row&7 == lane>>3 here, so swz = (lane>>3)<<4 uniformly.
    int srow = (lane >> 3);                       // 0..7, also row&7
    int scol = (((lane & 7) << 4) ^ (srow << 4)) >> 1;  // halfword offset in row
    auto STAGE = [&](int buf, int k0) {
#pragma unroll
        for (int p = 0; p < 4; ++p) {
            int r = p * 64 + wave * 8 + srow;
            const ushort* gA = Xb + (size_t)(rowBase + r) * D + k0 + scol;
            const ushort* gB = Xb + (size_t)(colBase + r) * D + k0 + scol;
            ushort* dA = &As[buf][p * 4096 + wave * 512];   // +lane*16B implicit
            ushort* dB = &Bs[buf][p * 4096 + wave * 512];
            __builtin_amdgcn_global_load_lds(GLB_PTR(gA), LDS_PTR(dA), 16, 0, 0);
            __builtin_amdgcn_global_load_lds(GLB_PTR(gB), LDS_PTR(dB), 16, 0, 0);
        }
    };

    int nt = D / GBK;   // 16
    STAGE(0, 0);
    STAGE(1, GBK);

    const char* AsB0 = (const char*)As[0];
    const char* BsB0 = (const char*)Bs[0];
    const char* AsB1 = (const char*)As[1];
    const char* BsB1 = (const char*)Bs[1];
    int l15 = lane & 15;
    int swz = (lane & 7) << 4;                 // rl&7 == lane&7 for all frags
    int kbase = (lane >> 4) * 16;              // 16B granule within 32-k half

    for (int t = 0; t < nt; ++t) {
        if (t < nt - 1) {
            asm volatile("s_waitcnt vmcnt(8)" ::: "memory");
        } else {
            asm volatile("s_waitcnt vmcnt(0)" ::: "memory");
        }
        __builtin_amdgcn_sched_barrier(0);
        asm volatile("s_barrier" ::: "memory");   // all waves' tile-t loads done

        const char* aB = (t & 1) ? AsB1 : AsB0;
        const char* bB = (t & 1) ? BsB1 : BsB0;

        __builtin_amdgcn_s_setprio(1);
#pragma unroll
        for (int kh = 0; kh < 2; ++kh) {
            int kb = kh * 64 + kbase;
            bf16x8 bF[4];
#pragma unroll
            for (int n2 = 0; n2 < 4; ++n2) {
                int brl = waveN * 64 + n2 * 16 + l15;
                bF[n2] = *reinterpret_cast<const bf16x8*>(bB + brl * 128 + (kb ^ swz));
            }
#pragma unroll
            for (int m = 0; m < 8; ++m) {
                int arl = waveM * 128 + m * 16 + l15;
                bf16x8 aF = *reinterpret_cast<const bf16x8*>(aB + arl * 128 + (kb ^ swz));
#pragma unroll
                for (int n2 = 0; n2 < 4; ++n2)
                    acc[m][n2] = __builtin_amdgcn_mfma_f32_16x16x32_bf16(aF, bF[n2], acc[m][n2], 0, 0, 0);
            }
        }
        __builtin_amdgcn_s_setprio(0);

        asm volatile("s_barrier" ::: "memory");   // all waves done reading slot t&1
        if (t + 2 < nt) STAGE(t & 1, (t + 2) * GBK);   // overwrite consumed slot
    }

    __syncthreads();   // tlist/s_cnt shared from here

    // epilogue: ballot-compact candidates into LDS tile list (no global atomics)
    int cr = (lane >> 4) * 4;
    int cc = lane & 15;
    unsigned long long lmask_lt = (1ull << lane) - 1ull;
#pragma unroll
    for (int m = 0; m < 8; ++m) {
#pragma unroll
        for (int n2 = 0; n2 < 4; ++n2) {
            int gcol = colBase + waveN * 64 + n2 * 16 + cc;
            float sqc = sq[gcol];
#pragma unroll
            for (int r = 0; r < 4; ++r) {
                int grow = rowBase + waveM * 128 + m * 16 + cr + r;
                float v = sq[grow] + sqc - 2.0f * acc[m][n2][r];
                bool pred = (v < P0SQ) && (grow != gcol);
                unsigned long long mask = __ballot(pred);
                if (mask) {
                    int leader = __ffsll((long long)mask) - 1;
                    int tot = __popcll(mask);
                    int base = 0;
                    if (lane == leader) base = atomicAdd(&s_cnt, tot);
                    base = __shfl(base, leader);
                    if (pred) {
                        int idx = base + __popcll(mask & lmask_lt);
                        if (idx < TCAP) {
                            float d = sqrtf(fmaxf(v, 1e-12f));
                            uint32_t pk = ((uint32_t)grow << 12) | (uint32_t)gcol;
                            float2 e; e.x = d; e.y = __builtin_bit_cast(float, pk);
                            tlist[idx] = e;
                        }
                    }
                }
            }
        }
    }
    __syncthreads();

    int cnt = s_cnt;
    int wr = min(cnt, TCAP);
    for (int e = tid; e < wr; e += 512)
        tileList[(size_t)wgid * TCAP + e] = tlist[e];
    if (tid == 0) tileCnt[wgid] = cnt;
    if (cnt > TCAP && tid < GBM)   // astronomically unlikely; rows lose records
        needFB[rowBase + tid] = 1;
}

// ---------------------------------------------------------------------------
// Kernel 3: binning — scatter tile lists into per-row candidate lists.
// ---------------------------------------------------------------------------
__global__ __launch_bounds__(256) void bin_kernel(const float2* __restrict__ tileList,
                                                  const int* __restrict__ tileCnt,
                                                  float2* __restrict__ cand,
                                                  int* __restrict__ cntArr) {
    int t = blockIdx.x;
    int cnt = min(tileCnt[t], TCAP);
    for (int e = threadIdx.x; e < cnt; e += 256) {
        float2 v = tileList[(size_t)t * TCAP + e];
        uint32_t pk = __builtin_bit_cast(uint32_t, v.y);
        int i = (int)(pk >> 12), j = (int)(pk & 4095u);
        int p = atomicAdd(&cntArr[i], 1);
        if (p < CAP) {
            float2 e1; e1.x = v.x; e1.y = __builtin_bit_cast(float, j);
            cand[(size_t)i * CAP + p] = e1;
        }
    }
}

// ---------------------------------------------------------------------------
// Kernel 4: per-row finalize from candidate lists. One WAVE per row (4/block).
// ---------------------------------------------------------------------------
__global__ __launch_bounds__(256) void rowfinal_kernel(const float2* __restrict__ cand,
                                                       const int* __restrict__ cntArr,
                                                       const int* __restrict__ targets,
                                                       const ushort* __restrict__ Xb,
                                                       const float* __restrict__ sq,
                                                       const int* __restrict__ f1,
                                                       const int* __restrict__ f2,
                                                       const int* __restrict__ lcnt,
                                                       int* __restrict__ needFB,
                                                       float* __restrict__ rowLoss,
                                                       int N, int D) {
    __shared__ float dbuf[4][CAP];
    int tid = threadIdx.x, lane = tid & 63, w = tid >> 6;
    int row = blockIdx.x * 4 + w;
    int ti = targets[row];
    int lc = lcnt[ti];
    bool validRow = (lc >= 2) && (lc < N);
    int cnt = cntArr[row];
    bool fb = (cnt < KSEL + 1) || (cnt > CAP);
    int lim = fb ? 0 : cnt;

    float ed[4]; int ej[4];
#pragma unroll
    for (int s = 0; s < 4; ++s) {
        int idx = lane + s * 64;
        bool in = (!fb) && (idx < cnt);
        if (in) {
            float2 e = cand[(size_t)row * CAP + idx];
            ed[s] = e.x; ej[s] = __builtin_bit_cast(int, e.y);
            dbuf[w][idx] = e.x;
        } else { ed[s] = BIGV; ej[s] = -1; }
    }
    __syncthreads();

    // exact rank: thr = value at rank KSEL (0-based) among candidates
    int rlo[4] = {0, 0, 0, 0}, req[4] = {0, 0, 0, 0};
    for (int q = 0; q < lim; ++q) {
        float u = dbuf[w][q];
#pragma unroll
        for (int s = 0; s < 4; ++s) {
            rlo[s] += (u < ed[s]);
            req[s] += (u == ed[s]);
        }
    }
    float thrc = BIGV;
#pragma unroll
    for (int s = 0; s < 4; ++s)
        if (ej[s] >= 0 && rlo[s] <= KSEL && KSEL < rlo[s] + req[s]) thrc = fminf(thrc, ed[s]);
    for (int off = 32; off; off >>= 1) thrc = fminf(thrc, __shfl_down(thrc, off));
    float thr = __shfl(thrc, 0);

    // masked sums over candidates (below-thr set fully contained in list)
    float posS = 0.f, negS = 0.f;
    int apb = 0;
#pragma unroll
    for (int s = 0; s < 4; ++s) {
        if (ej[s] >= 0 && ed[s] < thr) {
            bool same = (targets[ej[s]] == ti);
            float e = expf(ALPHA * (1.0f - ed[s]));
            if (same) { posS += e; apb = 1; }
            else negS += e;
        }
    }
    for (int off = 32; off; off >>= 1) {
        posS += __shfl_down(posS, off);
        negS += __shfl_down(negS, off);
        apb = max(apb, __shfl_down(apb, off));
    }

    // first-positive fallback distance (bf16 dot, fp32 accum)
    int fp = 0;
    float dot = 0.f;
    if (validRow) {
        fp = (row == f1[ti]) ? f2[ti] : f1[ti];
        const ushort* xr = Xb + (size_t)row * D;
        const ushort* xf = Xb + (size_t)fp * D;
        for (int c = lane; c < D / 4; c += 64) {
            ushort4 a = *reinterpret_cast<const ushort4*>(xr + (size_t)c * 4);
            ushort4 b = *reinterpret_cast<const ushort4*>(xf + (size_t)c * 4);
            dot += bfval(a.x) * bfval(b.x) + bfval(a.y) * bfval(b.y)
                 + bfval(a.z) * bfval(b.z) + bfval(a.w) * bfval(b.w);
        }
    }
    for (int off = 32; off; off >>= 1) dot += __shfl_down(dot, off);

    if (lane == 0) {
        if (fb) {
            needFB[row] = 1;
        } else if (!validRow) {
            rowLoss[row] = BIGV;
        } else {
            float fbD = sqrtf(fmaxf(sq[row] + sq[fp] - 2.0f * dot, 1e-12f));
            float posLogit = apb ? posS : expf(ALPHA * (1.0f - fbD));
            rowLoss[row] = -logf(posLogit / (posLogit + negS));
        }
    }
}

// ---------------------------------------------------------------------------
// Kernel 5: exact fallback (full-row recompute). Expected zero work.
// ---------------------------------------------------------------------------
__global__ __launch_bounds__(256) void fallback_kernel(const ushort* __restrict__ Xb,
                                                       const float* __restrict__ sq,
                                                       const int* __restrict__ targets,
                                                       const int* __restrict__ needFB,
                                                       const int* __restrict__ f1,
                                                       const int* __restrict__ f2,
                                                       const int* __restrict__ lcnt,
                                                       float* __restrict__ rowLoss,
                                                       int N, int D) {
    int row = blockIdx.x;
    if (!needFB[row]) return;

    __shared__ float xrow[1024];
    __shared__ float rowD[NMAX];
    __shared__ float sF[4];
    __shared__ int sI[4];
    int tid = threadIdx.x;

    for (int k = tid; k < D; k += 256) xrow[k] = bfval(Xb[(size_t)row * D + k]);
    __syncthreads();

    for (int j = tid; j < N; j += 256) {
        float dot = 0.f;
        const ushort* xj = Xb + (size_t)j * D;
        for (int k = 0; k < D; ++k) dot += xrow[k] * bfval(xj[k]);
        rowD[j] = (j == row) ? BIGV
                             : sqrtf(fmaxf(sq[row] + sq[j] - 2.0f * dot, 1e-12f));
    }
    __syncthreads();

    uint32_t lo = 0, hi = 0x40800000u;
    while (lo < hi) {
        uint32_t mid = (lo + hi) >> 1;
        float mv = __builtin_bit_cast(float, mid);
        int c = 0;
        for (int j = tid; j < N; j += 256) c += (rowD[j] <= mv);
        c = blockReduceSumI(c, sI);
        if (c >= KSEL + 1) hi = mid; else lo = mid + 1;
    }
    float thr = __builtin_bit_cast(float, hi);

    int ti = targets[row];
    int lc = lcnt[ti];
    bool validRow = (lc >= 2) && (lc < N);

    float posS = 0.f, negS = 0.f;
    int apb = 0;
    for (int j = tid; j < N; j += 256) {
        if (j == row) continue;
        float d = rowD[j];
        bool same = (targets[j] == ti);
        if (d < thr) {
            float e = expf(ALPHA * (1.0f - d));
            if (same) { posS += e; apb = 1; }
            else negS += e;
        }
    }
    posS = blockReduceSumF(posS, sF);
    negS = blockReduceSumF(negS, sF);
    apb = blockReduceMaxI(apb, sI);

    if (tid == 0) {
        if (!validRow) { rowLoss[row] = BIGV; return; }
        int fp = (row == f1[ti]) ? f2[ti] : f1[ti];
        float posLogit = apb ? posS : expf(ALPHA * (1.0f - rowD[fp]));
        rowLoss[row] = -logf(posLogit / (posLogit + negS));
    }
}

// ---------------------------------------------------------------------------
// Kernel 6: single-block reduction over rowLoss -> out[4]
// ---------------------------------------------------------------------------
__global__ __launch_bounds__(256) void reduce_kernel(const float* __restrict__ rowLoss,
                                                     float* __restrict__ out, int N) {
    __shared__ float sF[4];
    __shared__ int sI[4];
    int tid = threadIdx.x;
    float sumL = 0.f;
    int nValid = 0, nAcc = 0;
    for (int j = tid; j < N; j += 256) {
        float L = rowLoss[j];
        if (L != BIGV) {
            sumL += L;
            ++nValid;
            if (L < 0.6f) ++nAcc;
        }
    }
    sumL = blockReduceSumF(sumL, sF);
    nValid = blockReduceSumI(nValid, sI);
    nAcc = blockReduceSumI(nAcc, sI);
    if (tid == 0) {
        out[0] = (nValid > 0) ? sumL / (float)nValid : 0.f;
        out[1] = (float)nAcc / (float)N;
        out[2] = 0.f;
        out[3] = 0.f;
    }
}

// ---------------------------------------------------------------------------
extern "C" void kernel_launch(void* const* d_in, const int* in_sizes, int n_in,
                              void* d_out, int out_size, void* d_ws, size_t ws_size,
                              hipStream_t stream) {
    const float* X = (const float*)d_in[0];
    const int* targets = (const int*)d_in[1];
    float* out = (float*)d_out;

    int N = in_sizes[1];             // 4096
    int D = in_sizes[0] / N;         // 1024
    int tiles = N / GBM;             // 16
    int nTiles = tiles * tiles;      // 256

    // 8B-aligned float2 arrays first
    float2* cand     = (float2*)d_ws;                          // N*CAP f2      (7.3 MB)
    float2* tileList = cand + (size_t)N * CAP;                 // nTiles*TCAP   (3.4 MB)
    float*  sq       = (float*)(tileList + (size_t)nTiles * TCAP);
    float*  rowLoss  = sq + N;
    int*    cntArr   = (int*)(rowLoss + N);
    int*    needFB   = cntArr + N;
    int*    tileCnt  = needFB + N;                             // nTiles i32
    int*    f1       = tileCnt + nTiles;
    int*    f2       = f1 + 64;
    int*    lcnt     = f2 + 64;
    ushort* Xb       = (ushort*)(lcnt + 64 + 64);              // N*D bf16 (8 MB)

    hipMemsetAsync(cntArr, 0, N * sizeof(int), stream);
    hipMemsetAsync(needFB, 0, N * sizeof(int), stream);

    prep_kernel<<<N + 64, 256, 0, stream>>>(X, Xb, sq, targets, f1, f2, lcnt, D, N);

    distgemm_mfma<<<nTiles, 512, 0, stream>>>(Xb, sq, tileList, tileCnt, needFB, N, D);

    bin_kernel<<<nTiles, 256, 0, stream>>>(tileList, tileCnt, cand, cntArr);

    rowfinal_kernel<<<N / 4, 256, 0, stream>>>(cand, cntArr, targets, Xb, sq,
                                               f1, f2, lcnt, needFB, rowLoss, N, D);

    fallback_kernel<<<N, 256, 0, stream>>>(Xb, sq, targets, needFB,
                                           f1, f2, lcnt, rowLoss, N, D);

    reduce_kernel<<<1, 256, 0, stream>>>(rowLoss, out, N);
}

// Round 13
// 120.079 us; speedup vs baseline: 1.2725x; 1.1083x over previous
//
#include <hip/hip_runtime.h>
#include <hip/hip_bf16.h>
#include <cfloat>
#include <climits>
#include <cstdint>

#define ALPHA 30.0f
#define KSEL 16          // threshold = sorted[:,16] (17th smallest off-diag)
#define P0 1.368f        // candidate cutoff: E[cnt/row]≈82, P(cnt<17)~1e-13
#define P0SQ (P0 * P0)
#define CAP 224          // per-row candidate capacity (mean 82, +15 sigma)
#define TCAP 1664        // per-tile candidate capacity (256² tile: mean 1310, +9.9 sigma)
#define BIGV 1e30f
#define NMAX 4096

typedef __attribute__((ext_vector_type(8))) short bf16x8;
typedef __attribute__((ext_vector_type(4))) float f32x4;
typedef __attribute__((ext_vector_type(8))) int i32x8;
typedef __attribute__((ext_vector_type(4))) int i32x4;

#define LDS_PTR(p) ((__attribute__((address_space(3))) uint32_t*)(p))
#define GLB_PTR(p) ((const __attribute__((address_space(1))) uint32_t*)(p))

__device__ inline float bfval(ushort u) {
    return __builtin_bit_cast(float, (uint32_t)u << 16);
}

// ---------------------------------------------------------------------------
// block reduce helpers (256 threads, 4 waves)
// ---------------------------------------------------------------------------
__device__ inline float blockReduceSumF(float v, float* s) {
    for (int off = 32; off; off >>= 1) v += __shfl_down(v, off);
    int tid = threadIdx.x, wid = tid >> 6;
    if ((tid & 63) == 0) s[wid] = v;
    __syncthreads();
    float r;
    if (tid == 0) { r = s[0] + s[1] + s[2] + s[3]; s[0] = r; }
    __syncthreads();
    r = s[0];
    __syncthreads();
    return r;
}

__device__ inline int blockReduceSumI(int v, int* s) {
    for (int off = 32; off; off >>= 1) v += __shfl_down(v, off);
    int tid = threadIdx.x, wid = tid >> 6;
    if ((tid & 63) == 0) s[wid] = v;
    __syncthreads();
    int r;
    if (tid == 0) { r = s[0] + s[1] + s[2] + s[3]; s[0] = r; }
    __syncthreads();
    r = s[0];
    __syncthreads();
    return r;
}

__device__ inline int blockReduceMaxI(int v, int* s) {
    for (int off = 32; off; off >>= 1) v = max(v, __shfl_down(v, off));
    int tid = threadIdx.x, wid = tid >> 6;
    if ((tid & 63) == 0) s[wid] = v;
    __syncthreads();
    int r;
    if (tid == 0) { r = max(max(s[0], s[1]), max(s[2], s[3])); s[0] = r; }
    __syncthreads();
    r = s[0];
    __syncthreads();
    return r;
}

// ---------------------------------------------------------------------------
// Kernel 1: fused fp32 -> {bf16, fp8 e4m3 (x16)} + row sq-norm; blocks >= N
// do labelinfo. fp8 copy feeds the GEMM; bf16 copy feeds the tail dots.
// ---------------------------------------------------------------------------
__global__ __launch_bounds__(256) void prep_kernel(const float* __restrict__ X,
                                                   ushort* __restrict__ Xbf,
                                                   uint32_t* __restrict__ Xb8,
                                                   float* __restrict__ sq,
                                                   const int* __restrict__ targets,
                                                   int* __restrict__ f1,
                                                   int* __restrict__ f2,
                                                   int* __restrict__ lcnt,
                                                   int D, int N) {
    __shared__ float sw[4];
    __shared__ int s1[4], s2[4], sc[4];
    int tid = threadIdx.x;
    int wid = tid >> 6;

    if (blockIdx.x >= (unsigned)N) {
        int lbl = blockIdx.x - N;
        int a1 = INT_MAX, a2 = INT_MAX, c = 0;
        for (int j = tid; j < N; j += 256) {
            if (targets[j] == lbl) {
                ++c;
                if (j < a1) { a2 = a1; a1 = j; }
                else if (j < a2) a2 = j;
            }
        }
        for (int off = 32; off; off >>= 1) {
            int b1 = __shfl_down(a1, off), b2 = __shfl_down(a2, off), bc = __shfl_down(c, off);
            int m1 = min(a1, b1);
            int m2 = min(max(a1, b1), min(a2, b2));
            a1 = m1; a2 = m2; c += bc;
        }
        if ((tid & 63) == 0) { s1[wid] = a1; s2[wid] = a2; sc[wid] = c; }
        __syncthreads();
        if (tid == 0) {
            int r1 = s1[0], r2 = s2[0], rc = sc[0];
            for (int w = 1; w < 4; ++w) {
                int m1 = min(r1, s1[w]);
                int m2 = min(max(r1, s1[w]), min(r2, s2[w]));
                r1 = m1; r2 = m2; rc += sc[w];
            }
            f1[lbl] = r1; f2[lbl] = r2; lcnt[lbl] = rc;
        }
        return;
    }

    int row = blockIdx.x;
    const float4* xr = reinterpret_cast<const float4*>(X + (size_t)row * D);
    ushort4* xo = reinterpret_cast<ushort4*>(Xbf + (size_t)row * D);
    uint32_t* x8o = Xb8 + (size_t)row * (D / 4);
    float s = 0.f;
    for (int c = tid; c < D / 4; c += 256) {
        float4 v = xr[c];
        s += v.x * v.x + v.y * v.y + v.z * v.z + v.w * v.w;
        ushort4 o;
        uint32_t b;
        b = __builtin_bit_cast(uint32_t, v.x); o.x = (ushort)((b + 0x7FFF + ((b >> 16) & 1)) >> 16);
        b = __builtin_bit_cast(uint32_t, v.y); o.y = (ushort)((b + 0x7FFF + ((b >> 16) & 1)) >> 16);
        b = __builtin_bit_cast(uint32_t, v.z); o.z = (ushort)((b + 0x7FFF + ((b >> 16) & 1)) >> 16);
        b = __builtin_bit_cast(uint32_t, v.w); o.w = (ushort)((b + 0x7FFF + ((b >> 16) & 1)) >> 16);
        xo[c] = o;
        // fp8 e4m3 of 16*x (fits e4m3 sweet spot); GEMM divides acc by 256
        int pk = __builtin_amdgcn_cvt_pk_fp8_f32(v.x * 16.f, v.y * 16.f, 0, false);
        pk = __builtin_amdgcn_cvt_pk_fp8_f32(v.z * 16.f, v.w * 16.f, pk, true);
        x8o[c] = (uint32_t)pk;
    }
    for (int off = 32; off; off >>= 1) s += __shfl_down(s, off);
    if ((tid & 63) == 0) sw[wid] = s;
    __syncthreads();
    if (tid == 0) sq[row] = sw[0] + sw[1] + sw[2] + sw[3];
}

// ---------------------------------------------------------------------------
// Kernel 2: 256x256-tile fp8 MFMA GEMM (mfma_scale 16x16x128, neutral scale),
// BK=128 elements (128 B LDS rows) -> only 8 K-steps. Ring-2 K-slots with
// counted vmcnt (never 0 mid-loop) + raw s_barrier; T2 XOR-swizzle with
// linear LDS dest + inverse-swizzled global source (R11-proven, conflicts=0).
// acc holds 256*dot (inputs pre-scaled by 16); epilogue divides.
// ---------------------------------------------------------------------------
#define GBM 256
#define GBK 128
__global__ __launch_bounds__(512, 2) void distgemm_mfma(const uint8_t* __restrict__ Xb8,
                                                        const float* __restrict__ sq,
                                                        float2* __restrict__ tileList,
                                                        int* __restrict__ tileCnt,
                                                        int* __restrict__ needFB,
                                                        int N, int D) {
    __shared__ uint8_t As[2][GBM * GBK];   // 2 x 32 KB
    __shared__ uint8_t Bs[2][GBM * GBK];   // 2 x 32 KB
    __shared__ float2 tlist[TCAP];         // 13 KB
    __shared__ int s_cnt;

    // XCD swizzle: 256 blocks, 8 XCDs -> 32 consecutive wgids per XCD.
    int wg = blockIdx.x;
    int wgid = (wg & 7) * 32 + (wg >> 3);
    int by = wgid >> 4, bx = wgid & 15;

    int tid = threadIdx.x;
    int lane = tid & 63;
    int wave = tid >> 6;        // 0..7
    int waveM = wave >> 2;      // 0..1  -> 128-row half
    int waveN = wave & 3;       // 0..3  -> 64-col quarter

    int rowBase = by * GBM;
    int colBase = bx * GBM;

    if (tid == 0) s_cnt = 0;

    f32x4 acc[8][4];
#pragma unroll
    for (int m = 0; m < 8; ++m)
#pragma unroll
        for (int n2 = 0; n2 < 4; ++n2) {
            f32x4 z = {0.f, 0.f, 0.f, 0.f};
            acc[m][n2] = z;
        }

    // staging: per K-tile 32KB A + 32KB B; 8 loads/wave (4 rounds x {A,B}).
    // round p: rows p*64 + wave*8 + (lane>>3); within-row 16B granule (lane&7),
    // global source granule = (lane&7) ^ (row&7)  [row&7 == lane>>3 here].
    int srow = lane >> 3;                              // 0..7, == row&7
    int sgb = ((lane & 7) << 4) ^ (srow << 4);         // source byte offset in row
    auto STAGE = [&](int buf, int k0) {                // k0 in elements (=bytes)
#pragma unroll
        for (int p = 0; p < 4; ++p) {
            int r = p * 64 + wave * 8 + srow;
            const uint8_t* gA = Xb8 + (size_t)(rowBase + r) * D + k0 + sgb;
            const uint8_t* gB = Xb8 + (size_t)(colBase + r) * D + k0 + sgb;
            uint8_t* dA = &As[buf][p * 8192 + wave * 1024];   // + lane*16 implicit
            uint8_t* dB = &Bs[buf][p * 8192 + wave * 1024];
            __builtin_amdgcn_global_load_lds(GLB_PTR(gA), LDS_PTR(dA), 16, 0, 0);
            __builtin_amdgcn_global_load_lds(GLB_PTR(gB), LDS_PTR(dB), 16, 0, 0);
        }
    };

    int nt = D / GBK;   // 8
    STAGE(0, 0);
    STAGE(1, GBK);

    int l15 = lane & 15;
    int kq32 = (lane >> 4) * 32;          // k-byte quarter base
    int rswz = (l15 & 7) << 4;            // (row&7)<<4, uniform across frags

    for (int t = 0; t < nt; ++t) {
        if (t < nt - 1) {
            asm volatile("s_waitcnt vmcnt(8)" ::: "memory");
        } else {
            asm volatile("s_waitcnt vmcnt(0)" ::: "memory");
        }
        __builtin_amdgcn_sched_barrier(0);
        asm volatile("s_barrier" ::: "memory");   // all waves' tile-t loads done

        const uint8_t* aB = As[t & 1];
        const uint8_t* bB = Bs[t & 1];

        __builtin_amdgcn_s_setprio(1);
        i32x8 bF[4];
#pragma unroll
        for (int n2 = 0; n2 < 4; ++n2) {
            int brl = waveN * 64 + n2 * 16 + l15;
            const uint8_t* base = bB + brl * 128;
            i32x4 lo = *reinterpret_cast<const i32x4*>(base + ((kq32) ^ rswz));
            i32x4 hi = *reinterpret_cast<const i32x4*>(base + ((kq32 + 16) ^ rswz));
            i32x8 f = {lo[0], lo[1], lo[2], lo[3], hi[0], hi[1], hi[2], hi[3]};
            bF[n2] = f;
        }
#pragma unroll
        for (int m = 0; m < 8; ++m) {
            int arl = waveM * 128 + m * 16 + l15;
            const uint8_t* base = aB + arl * 128;
            i32x4 lo = *reinterpret_cast<const i32x4*>(base + ((kq32) ^ rswz));
            i32x4 hi = *reinterpret_cast<const i32x4*>(base + ((kq32 + 16) ^ rswz));
            i32x8 aF = {lo[0], lo[1], lo[2], lo[3], hi[0], hi[1], hi[2], hi[3]};
#pragma unroll
            for (int n2 = 0; n2 < 4; ++n2)
                acc[m][n2] = __builtin_amdgcn_mfma_scale_f32_16x16x128_f8f6f4(
                    aF, bF[n2], acc[m][n2], 0, 0, 0, 0x7F, 0, 0x7F);
        }
        __builtin_amdgcn_s_setprio(0);

        asm volatile("s_barrier" ::: "memory");   // all waves done reading slot
        if (t + 2 < nt) STAGE(t & 1, (t + 2) * GBK);
    }

    __syncthreads();   // tlist/s_cnt shared from here

    // epilogue: acc = 256*dot -> v = sqi+sqj-2*dot = sqi+sqj-acc/128
    int cr = (lane >> 4) * 4;
    int cc = lane & 15;
    unsigned long long lmask_lt = (1ull << lane) - 1ull;
#pragma unroll
    for (int m = 0; m < 8; ++m) {
#pragma unroll
        for (int n2 = 0; n2 < 4; ++n2) {
            int gcol = colBase + waveN * 64 + n2 * 16 + cc;
            float sqc = sq[gcol];
#pragma unroll
            for (int r = 0; r < 4; ++r) {
                int grow = rowBase + waveM * 128 + m * 16 + cr + r;
                float v = sq[grow] + sqc - acc[m][n2][r] * 0.0078125f;  // 2/256
                bool pred = (v < P0SQ) && (grow != gcol);
                unsigned long long mask = __ballot(pred);
                if (mask) {
                    int leader = __ffsll((long long)mask) - 1;
                    int tot = __popcll(mask);
                    int base = 0;
                    if (lane == leader) base = atomicAdd(&s_cnt, tot);
                    base = __shfl(base, leader);
                    if (pred) {
                        int idx = base + __popcll(mask & lmask_lt);
                        if (idx < TCAP) {
                            float d = sqrtf(fmaxf(v, 1e-12f));
                            uint32_t pk = ((uint32_t)grow << 12) | (uint32_t)gcol;
                            float2 e; e.x = d; e.y = __builtin_bit_cast(float, pk);
                            tlist[idx] = e;
                        }
                    }
                }
            }
        }
    }
    __syncthreads();

    int cnt = s_cnt;
    int wr = min(cnt, TCAP);
    for (int e = tid; e < wr; e += 512)
        tileList[(size_t)wgid * TCAP + e] = tlist[e];
    if (tid == 0) tileCnt[wgid] = cnt;
    if (cnt > TCAP && tid < GBM)   // astronomically unlikely; rows lose records
        needFB[rowBase + tid] = 1;
}

// ---------------------------------------------------------------------------
// Kernel 3: binning — scatter tile lists into per-row candidate lists.
// ---------------------------------------------------------------------------
__global__ __launch_bounds__(256) void bin_kernel(const float2* __restrict__ tileList,
                                                  const int* __restrict__ tileCnt,
                                                  float2* __restrict__ cand,
                                                  int* __restrict__ cntArr) {
    int t = blockIdx.x;
    int cnt = min(tileCnt[t], TCAP);
    for (int e = threadIdx.x; e < cnt; e += 256) {
        float2 v = tileList[(size_t)t * TCAP + e];
        uint32_t pk = __builtin_bit_cast(uint32_t, v.y);
        int i = (int)(pk >> 12), j = (int)(pk & 4095u);
        int p = atomicAdd(&cntArr[i], 1);
        if (p < CAP) {
            float2 e1; e1.x = v.x; e1.y = __builtin_bit_cast(float, j);
            cand[(size_t)i * CAP + p] = e1;
        }
    }
}

// ---------------------------------------------------------------------------
// Kernel 4: per-row finalize from candidate lists. One WAVE per row (4/block).
// ---------------------------------------------------------------------------
__global__ __launch_bounds__(256) void rowfinal_kernel(const float2* __restrict__ cand,
                                                       const int* __restrict__ cntArr,
                                                       const int* __restrict__ targets,
                                                       const ushort* __restrict__ Xbf,
                                                       const float* __restrict__ sq,
                                                       const int* __restrict__ f1,
                                                       const int* __restrict__ f2,
                                                       const int* __restrict__ lcnt,
                                                       int* __restrict__ needFB,
                                                       float* __restrict__ rowLoss,
                                                       int N, int D) {
    __shared__ float dbuf[4][CAP];
    int tid = threadIdx.x, lane = tid & 63, w = tid >> 6;
    int row = blockIdx.x * 4 + w;
    int ti = targets[row];
    int lc = lcnt[ti];
    bool validRow = (lc >= 2) && (lc < N);
    int cnt = cntArr[row];
    bool fb = (cnt < KSEL + 1) || (cnt > CAP);
    int lim = fb ? 0 : cnt;

    float ed[4]; int ej[4];
#pragma unroll
    for (int s = 0; s < 4; ++s) {
        int idx = lane + s * 64;
        bool in = (!fb) && (idx < cnt);
        if (in) {
            float2 e = cand[(size_t)row * CAP + idx];
            ed[s] = e.x; ej[s] = __builtin_bit_cast(int, e.y);
            dbuf[w][idx] = e.x;
        } else { ed[s] = BIGV; ej[s] = -1; }
    }
    __syncthreads();

    // exact rank: thr = value at rank KSEL (0-based) among candidates
    int rlo[4] = {0, 0, 0, 0}, req[4] = {0, 0, 0, 0};
    for (int q = 0; q < lim; ++q) {
        float u = dbuf[w][q];
#pragma unroll
        for (int s = 0; s < 4; ++s) {
            rlo[s] += (u < ed[s]);
            req[s] += (u == ed[s]);
        }
    }
    float thrc = BIGV;
#pragma unroll
    for (int s = 0; s < 4; ++s)
        if (ej[s] >= 0 && rlo[s] <= KSEL && KSEL < rlo[s] + req[s]) thrc = fminf(thrc, ed[s]);
    for (int off = 32; off; off >>= 1) thrc = fminf(thrc, __shfl_down(thrc, off));
    float thr = __shfl(thrc, 0);

    // masked sums over candidates (below-thr set fully contained in list)
    float posS = 0.f, negS = 0.f;
    int apb = 0;
#pragma unroll
    for (int s = 0; s < 4; ++s) {
        if (ej[s] >= 0 && ed[s] < thr) {
            bool same = (targets[ej[s]] == ti);
            float e = expf(ALPHA * (1.0f - ed[s]));
            if (same) { posS += e; apb = 1; }
            else negS += e;
        }
    }
    for (int off = 32; off; off >>= 1) {
        posS += __shfl_down(posS, off);
        negS += __shfl_down(negS, off);
        apb = max(apb, __shfl_down(apb, off));
    }

    // first-positive fallback distance (bf16 dot, fp32 accum)
    int fp = 0;
    float dot = 0.f;
    if (validRow) {
        fp = (row == f1[ti]) ? f2[ti] : f1[ti];
        const ushort* xr = Xbf + (size_t)row * D;
        const ushort* xf = Xbf + (size_t)fp * D;
        for (int c = lane; c < D / 4; c += 64) {
            ushort4 a = *reinterpret_cast<const ushort4*>(xr + (size_t)c * 4);
            ushort4 b = *reinterpret_cast<const ushort4*>(xf + (size_t)c * 4);
            dot += bfval(a.x) * bfval(b.x) + bfval(a.y) * bfval(b.y)
                 + bfval(a.z) * bfval(b.z) + bfval(a.w) * bfval(b.w);
        }
    }
    for (int off = 32; off; off >>= 1) dot += __shfl_down(dot, off);

    if (lane == 0) {
        if (fb) {
            needFB[row] = 1;
        } else if (!validRow) {
            rowLoss[row] = BIGV;
        } else {
            float fbD = sqrtf(fmaxf(sq[row] + sq[fp] - 2.0f * dot, 1e-12f));
            float posLogit = apb ? posS : expf(ALPHA * (1.0f - fbD));
            rowLoss[row] = -logf(posLogit / (posLogit + negS));
        }
    }
}

// ---------------------------------------------------------------------------
// Kernel 5: exact fallback (full-row recompute, bf16). Expected zero work.
// ---------------------------------------------------------------------------
__global__ __launch_bounds__(256) void fallback_kernel(const ushort* __restrict__ Xbf,
                                                       const float* __restrict__ sq,
                                                       const int* __restrict__ targets,
                                                       const int* __restrict__ needFB,
                                                       const int* __restrict__ f1,
                                                       const int* __restrict__ f2,
                                                       const int* __restrict__ lcnt,
                                                       float* __restrict__ rowLoss,
                                                       int N, int D) {
    int row = blockIdx.x;
    if (!needFB[row]) return;

    __shared__ float xrow[1024];
    __shared__ float rowD[NMAX];
    __shared__ float sF[4];
    __shared__ int sI[4];
    int tid = threadIdx.x;

    for (int k = tid; k < D; k += 256) xrow[k] = bfval(Xbf[(size_t)row * D + k]);
    __syncthreads();

    for (int j = tid; j < N; j += 256) {
        float dot = 0.f;
        const ushort* xj = Xbf + (size_t)j * D;
        for (int k = 0; k < D; ++k) dot += xrow[k] * bfval(xj[k]);
        rowD[j] = (j == row) ? BIGV
                             : sqrtf(fmaxf(sq[row] + sq[j] - 2.0f * dot, 1e-12f));
    }
    __syncthreads();

    uint32_t lo = 0, hi = 0x40800000u;
    while (lo < hi) {
        uint32_t mid = (lo + hi) >> 1;
        float mv = __builtin_bit_cast(float, mid);
        int c = 0;
        for (int j = tid; j < N; j += 256) c += (rowD[j] <= mv);
        c = blockReduceSumI(c, sI);
        if (c >= KSEL + 1) hi = mid; else lo = mid + 1;
    }
    float thr = __builtin_bit_cast(float, hi);

    int ti = targets[row];
    int lc = lcnt[ti];
    bool validRow = (lc >= 2) && (lc < N);

    float posS = 0.f, negS = 0.f;
    int apb = 0;
    for (int j = tid; j < N; j += 256) {
        if (j == row) continue;
        float d = rowD[j];
        bool same = (targets[j] == ti);
        if (d < thr) {
            float e = expf(ALPHA * (1.0f - d));
            if (same) { posS += e; apb = 1; }
            else negS += e;
        }
    }
    posS = blockReduceSumF(posS, sF);
    negS = blockReduceSumF(negS, sF);
    apb = blockReduceMaxI(apb, sI);

    if (tid == 0) {
        if (!validRow) { rowLoss[row] = BIGV; return; }
        int fp = (row == f1[ti]) ? f2[ti] : f1[ti];
        float posLogit = apb ? posS : expf(ALPHA * (1.0f - rowD[fp]));
        rowLoss[row] = -logf(posLogit / (posLogit + negS));
    }
}

// ---------------------------------------------------------------------------
// Kernel 6: single-block reduction over rowLoss -> out[4]
// ---------------------------------------------------------------------------
__global__ __launch_bounds__(256) void reduce_kernel(const float* __restrict__ rowLoss,
                                                     float* __restrict__ out, int N) {
    __shared__ float sF[4];
    __shared__ int sI[4];
    int tid = threadIdx.x;
    float sumL = 0.f;
    int nValid = 0, nAcc = 0;
    for (int j = tid; j < N; j += 256) {
        float L = rowLoss[j];
        if (L != BIGV) {
            sumL += L;
            ++nValid;
            if (L < 0.6f) ++nAcc;
        }
    }
    sumL = blockReduceSumF(sumL, sF);
    nValid = blockReduceSumI(nValid, sI);
    nAcc = blockReduceSumI(nAcc, sI);
    if (tid == 0) {
        out[0] = (nValid > 0) ? sumL / (float)nValid : 0.f;
        out[1] = (float)nAcc / (float)N;
        out[2] = 0.f;
        out[3] = 0.f;
    }
}

// ---------------------------------------------------------------------------
extern "C" void kernel_launch(void* const* d_in, const int* in_sizes, int n_in,
                              void* d_out, int out_size, void* d_ws, size_t ws_size,
                              hipStream_t stream) {
    const float* X = (const float*)d_in[0];
    const int* targets = (const int*)d_in[1];
    float* out = (float*)d_out;

    int N = in_sizes[1];             // 4096
    int D = in_sizes[0] / N;         // 1024
    int tiles = N / GBM;             // 16
    int nTiles = tiles * tiles;      // 256

    // 8B-aligned float2 arrays first
    float2* cand     = (float2*)d_ws;                          // N*CAP f2      (7.3 MB)
    float2* tileList = cand + (size_t)N * CAP;                 // nTiles*TCAP   (3.4 MB)
    float*  sq       = (float*)(tileList + (size_t)nTiles * TCAP);
    float*  rowLoss  = sq + N;
    int*    cntArr   = (int*)(rowLoss + N);
    int*    needFB   = cntArr + N;
    int*    tileCnt  = needFB + N;                             // nTiles i32
    int*    f1       = tileCnt + nTiles;
    int*    f2       = f1 + 64;
    int*    lcnt     = f2 + 64;
    ushort* Xbf      = (ushort*)(lcnt + 64 + 64);              // N*D bf16 (8 MB)
    uint32_t* Xb8    = (uint32_t*)(Xbf + (size_t)N * D);       // N*D fp8  (4 MB)

    hipMemsetAsync(cntArr, 0, N * sizeof(int), stream);
    hipMemsetAsync(needFB, 0, N * sizeof(int), stream);

    prep_kernel<<<N + 64, 256, 0, stream>>>(X, Xbf, Xb8, sq, targets, f1, f2, lcnt, D, N);

    distgemm_mfma<<<nTiles, 512, 0, stream>>>((const uint8_t*)Xb8, sq, tileList,
                                              tileCnt, needFB, N, D);

    bin_kernel<<<nTiles, 256, 0, stream>>>(tileList, tileCnt, cand, cntArr);

    rowfinal_kernel<<<N / 4, 256, 0, stream>>>(cand, cntArr, targets, Xbf, sq,
                                               f1, f2, lcnt, needFB, rowLoss, N, D);

    fallback_kernel<<<N, 256, 0, stream>>>(Xbf, sq, targets, needFB,
                                           f1, f2, lcnt, rowLoss, N, D);

    reduce_kernel<<<1, 256, 0, stream>>>(rowLoss, out, N);
}